// Round 3
// baseline (198.706 us; speedup 1.0000x reference)
//
#include <hip/hip_runtime.h>
#include <hip/hip_bf16.h>

typedef __hip_bfloat16 bf16;
typedef __attribute__((ext_vector_type(4))) float f32x4;
typedef __attribute__((ext_vector_type(8))) short bf16x8;  // 8 bf16 in 4 VGPRs

// ---------------------------------------------------------------------------
// helpers
// ---------------------------------------------------------------------------
__device__ __forceinline__ void gload_lds16(const bf16* g, bf16* l) {
  __builtin_amdgcn_global_load_lds(
      (const __attribute__((address_space(1))) unsigned int*)(const void*)g,
      (__attribute__((address_space(3))) unsigned int*)(void*)l,
      16, 0, 0);
}

// XCD-contiguous bijective swizzle; REQUIRES nwg % 8 == 0.
__device__ __forceinline__ int xcd_swz(int orig, int nwg) {
  return (orig & 7) * (nwg >> 3) + (orig >> 3);
}

// ---------------------------------------------------------------------------
// fp32 -> bf16 conversion (vectorized, exact grid)
// ---------------------------------------------------------------------------
__global__ void cvt_f32_bf16(const float* __restrict__ in, bf16* __restrict__ out) {
  size_t i = ((size_t)blockIdx.x * 256 + threadIdx.x) * 4;
  float4 v = *reinterpret_cast<const float4*>(in + i);
  bf16 o[4] = {__float2bfloat16(v.x), __float2bfloat16(v.y),
               __float2bfloat16(v.z), __float2bfloat16(v.w)};
  *reinterpret_cast<ushort4*>(out + i) = *reinterpret_cast<const ushort4*>(o);
}

// ---------------------------------------------------------------------------
// addend[w][h][row][col64] = masked ? mask : table[pos_idx, h] ; col>=49 -> -1e30
// handles pos_idx stored as int32 OR int64 (odd-word-zero probe)
// ---------------------------------------------------------------------------
__global__ void build_addend(const float* __restrict__ mask, const int* __restrict__ pos,
                             const float* __restrict__ table, float* __restrict__ out) {
  int idx = blockIdx.x * 256 + threadIdx.x;   // total 64*12*49*64 = 2,408,448
  int col = idx & 63;
  int rh  = idx >> 6;
  int row = rh % 49;
  int h   = (rh / 49) % 12;
  int w   = rh / (49 * 12);
  float v = -1e30f;
  if (col < 49) {
    float m = mask[(w * 49 + row) * 49 + col];
    if (m != 0.0f) {
      v = m;
    } else {
      bool is64 = (pos[1] == 0) & (pos[3] == 0) & (pos[5] == 0) & (pos[7] == 0) &
                  (pos[9] == 0) & (pos[11] == 0) & (pos[13] == 0) & (pos[15] == 0);
      int pi = (w * 49 + row) * 49 + col;
      int p = is64 ? pos[2 * pi] : pos[pi];
      v = table[p * 12 + h];
    }
  }
  out[idx] = v;
}

// ---------------------------------------------------------------------------
// GEMM: C[M,N] = A[M,K] @ B[N,K]^T + bias[N]   (A,B bf16 row-major K-contig)
// 128x128 tile, BK=64, 4 waves (2x2 of 64x64), global_load_lds width 16.
// M%128==0, N%128==0, K%64==0, grid%8==0 guaranteed by caller.
// ---------------------------------------------------------------------------
template <bool OUT_BF16>
__global__ __launch_bounds__(256) void gemm_bt(
    const bf16* __restrict__ A, const bf16* __restrict__ Bm,
    const float* __restrict__ bias, void* __restrict__ Cout,
    int M, int N, int K, int nbn, int nwg) {
  __shared__ bf16 As[128 * 64];
  __shared__ bf16 Bs[128 * 64];
  const int t = threadIdx.x;
  const int lane = t & 63;
  const int w = t >> 6, wr = w >> 1, wc = w & 1;
  const int lid = xcd_swz(blockIdx.x, nwg);
  const int bm = lid / nbn, bn = lid % nbn;
  const int lr = lane & 15, lg = lane >> 4;

  // staging: thread t covers row (q*32 + t>>3), cols (t&7)*8 .. +8, q=0..3
  const bf16* ag = A + ((size_t)(bm * 128 + (t >> 3))) * K + (t & 7) * 8;
  const bf16* bg = Bm + ((size_t)(bn * 128 + (t >> 3))) * K + (t & 7) * 8;
  bf16* al = As + t * 8;
  bf16* bl = Bs + t * 8;
  const size_t rstep = (size_t)32 * K;

  f32x4 acc[4][4] = {};

  for (int k0 = 0; k0 < K; k0 += 64) {
#pragma unroll
    for (int q = 0; q < 4; q++) {
      gload_lds16(ag + k0 + q * rstep, al + q * 2048);
      gload_lds16(bg + k0 + q * rstep, bl + q * 2048);
    }
    __syncthreads();
#pragma unroll
    for (int kk = 0; kk < 64; kk += 32) {
      bf16x8 af[4], bff[4];
      const bf16* ab = As + (wr * 64 + lr) * 64 + kk + lg * 8;
      const bf16* bb = Bs + (wc * 64 + lr) * 64 + kk + lg * 8;
#pragma unroll
      for (int i = 0; i < 4; i++) af[i] = *reinterpret_cast<const bf16x8*>(ab + i * 16 * 64);
#pragma unroll
      for (int j = 0; j < 4; j++) bff[j] = *reinterpret_cast<const bf16x8*>(bb + j * 16 * 64);
#pragma unroll
      for (int i = 0; i < 4; i++)
#pragma unroll
        for (int j = 0; j < 4; j++)
          acc[i][j] = __builtin_amdgcn_mfma_f32_16x16x32_bf16(af[i], bff[j], acc[i][j], 0, 0, 0);
    }
    __syncthreads();
  }

#pragma unroll
  for (int i = 0; i < 4; i++) {
    int row0 = bm * 128 + wr * 64 + i * 16 + lg * 4;
#pragma unroll
    for (int j = 0; j < 4; j++) {
      int col = bn * 128 + wc * 64 + j * 16 + lr;
      float bv = bias[col];
#pragma unroll
      for (int r = 0; r < 4; r++) {
        float v = acc[i][j][r] + bv;
        if (OUT_BF16)
          ((bf16*)Cout)[(size_t)(row0 + r) * N + col] = __float2bfloat16(v);
        else
          ((float*)Cout)[(size_t)(row0 + r) * N + col] = v;
      }
    }
  }
}

// ---------------------------------------------------------------------------
// fused window attention: 1 wave per (b_, h). 49x49 scores padded to 64x64.
// qkv layout: [50176][1152] bf16, cols [0,384)=Q, [384,768)=K, [768,1152)=V.
// Computes S^T = mfma(K, Q) so the softmax reduction axis (k) is lane-local:
// lane holds, for q = qj*16 + (lane&15), k values {ki*16 + (lane>>4)*4 + r}.
// ---------------------------------------------------------------------------
__global__ __launch_bounds__(64) void attn_kernel(
    const bf16* __restrict__ qkv, const float* __restrict__ addend,
    bf16* __restrict__ attn_out) {
  const int bid = xcd_swz(blockIdx.x, 12288);   // 12 consecutive bids share a window
  const int b = bid / 12;
  const int h = bid % 12;
  const int w = b & 63;
  const int lane = threadIdx.x;
  const int lr = lane & 15, lg = lane >> 4;
  const float scale = 0.17677669529663687f;  // 32^-0.5

  __shared__ ushort p_lds[64][72];  // P[q][k], normalized, bf16
  __shared__ ushort vT[32][72];     // V^T[d][k]

  const size_t base = (size_t)b * 49 * 1152;

  // --- Q, K fragments straight from global (rows >= 49 clamped to 48)
  bf16x8 qf[4], kf[4];
#pragma unroll
  for (int i = 0; i < 4; i++) {
    int rw = i * 16 + lr;
    int row = rw < 49 ? rw : 48;
    qf[i] = *reinterpret_cast<const bf16x8*>(qkv + base + (size_t)row * 1152 + h * 32 + lg * 8);
    kf[i] = *reinterpret_cast<const bf16x8*>(qkv + base + (size_t)row * 1152 + 384 + h * 32 + lg * 8);
  }

  // --- stage V transposed into LDS: vT[d][k] = V[k][d]; pad k>=49 with 0
  if (lane < 49) {
#pragma unroll
    for (int c4 = 0; c4 < 4; c4++) {
      bf16x8 vv = *reinterpret_cast<const bf16x8*>(
          qkv + base + (size_t)lane * 1152 + 768 + h * 32 + c4 * 8);
#pragma unroll
      for (int cc = 0; cc < 8; cc++) vT[c4 * 8 + cc][lane] = (ushort)vv[cc];
    }
  } else {
#pragma unroll
    for (int c = 0; c < 32; c++) vT[c][lane] = 0;
  }

  // --- S^T = K @ Q^T: acc[ki][qj], C-layout row = k = ki*16+lg*4+r, col = q = qj*16+lr
  f32x4 acc[4][4] = {};
#pragma unroll
  for (int ki = 0; ki < 4; ki++)
#pragma unroll
    for (int qj = 0; qj < 4; qj++)
      acc[ki][qj] = __builtin_amdgcn_mfma_f32_16x16x32_bf16(kf[ki], qf[qj], acc[ki][qj], 0, 0, 0);

  // --- softmax over k (lane-local): per qj this lane owns 16 k-values of row q
  const float* add_base = addend + (size_t)(w * 12 + h) * 49 * 64;
#pragma unroll
  for (int qj = 0; qj < 4; qj++) {
    int q = qj * 16 + lr;
    int qc = q < 49 ? q : 48;
    const float* ab_ = add_base + qc * 64;
    float v[16];
    float mx = -1e38f;
#pragma unroll
    for (int ki = 0; ki < 4; ki++) {
      float4 ad = *reinterpret_cast<const float4*>(ab_ + ki * 16 + lg * 4);
      v[ki * 4 + 0] = acc[ki][qj][0] * scale + ad.x;
      v[ki * 4 + 1] = acc[ki][qj][1] * scale + ad.y;
      v[ki * 4 + 2] = acc[ki][qj][2] * scale + ad.z;
      v[ki * 4 + 3] = acc[ki][qj][3] * scale + ad.w;
    }
#pragma unroll
    for (int u = 0; u < 16; u++) mx = fmaxf(mx, v[u]);
    mx = fmaxf(mx, __shfl_xor(mx, 16, 64));
    mx = fmaxf(mx, __shfl_xor(mx, 32, 64));
    float sum = 0.f;
#pragma unroll
    for (int u = 0; u < 16; u++) {
      v[u] = __expf(v[u] - mx);
      sum += v[u];
    }
    sum += __shfl_xor(sum, 16, 64);
    sum += __shfl_xor(sum, 32, 64);
    float rs = 1.0f / sum;
    // normalized P, k-contiguous packs of 4 -> b64 writes
#pragma unroll
    for (int ki = 0; ki < 4; ki++) {
      ushort4 u4;
      u4.x = __bfloat16_as_ushort(__float2bfloat16(v[ki * 4 + 0] * rs));
      u4.y = __bfloat16_as_ushort(__float2bfloat16(v[ki * 4 + 1] * rs));
      u4.z = __bfloat16_as_ushort(__float2bfloat16(v[ki * 4 + 2] * rs));
      u4.w = __bfloat16_as_ushort(__float2bfloat16(v[ki * 4 + 3] * rs));
      *reinterpret_cast<ushort4*>(&p_lds[q][ki * 16 + lg * 4]) = u4;
    }
  }
  __syncthreads();

  // --- O = P @ V  (K-dim 64, 2 steps of 32); pf is A-frag P[q=lr][k contiguous]
  f32x4 acc2[4][2] = {};
#pragma unroll
  for (int ks = 0; ks < 2; ks++) {
    bf16x8 vf[2];
#pragma unroll
    for (int dt = 0; dt < 2; dt++)
      vf[dt] = *reinterpret_cast<const bf16x8*>(&vT[dt * 16 + lr][ks * 32 + lg * 8]);
#pragma unroll
    for (int i = 0; i < 4; i++) {
      bf16x8 pf = *reinterpret_cast<const bf16x8*>(&p_lds[i * 16 + lr][ks * 32 + lg * 8]);
#pragma unroll
      for (int dt = 0; dt < 2; dt++)
        acc2[i][dt] = __builtin_amdgcn_mfma_f32_16x16x32_bf16(pf, vf[dt], acc2[i][dt], 0, 0, 0);
    }
  }

  // --- store attn_out (bf16); P was pre-normalized
#pragma unroll
  for (int i = 0; i < 4; i++)
#pragma unroll
    for (int r = 0; r < 4; r++) {
      int row = i * 16 + lg * 4 + r;
      if (row < 49) {
#pragma unroll
        for (int dt = 0; dt < 2; dt++) {
          int col = h * 32 + dt * 16 + lr;
          attn_out[((size_t)b * 49 + row) * 384 + col] = __float2bfloat16(acc2[i][dt][r]);
        }
      }
    }
}

// ---------------------------------------------------------------------------
// launch
// ---------------------------------------------------------------------------
extern "C" void kernel_launch(void* const* d_in, const int* in_sizes, int n_in,
                              void* d_out, int out_size, void* d_ws, size_t ws_size,
                              hipStream_t stream) {
  const float* x      = (const float*)d_in[0];
  const float* mask   = (const float*)d_in[1];
  const int*   posidx = (const int*)d_in[2];
  const float* table  = (const float*)d_in[3];
  const float* w_qkv  = (const float*)d_in[4];
  const float* b_qkv  = (const float*)d_in[5];
  const float* w_proj = (const float*)d_in[6];
  const float* b_proj = (const float*)d_in[7];
  float* out = (float*)d_out;

  char* ws = (char*)d_ws;
  bf16*  xb     = (bf16*)(ws + 0);            // 50176*384   bf16 = 38,535,168 B
  bf16*  wqkvb  = (bf16*)(ws + 38535168);     // 1152*384    bf16 =    884,736 B
  bf16*  wprojb = (bf16*)(ws + 39419904);     // 384*384     bf16 =    294,912 B
  bf16*  qkv    = (bf16*)(ws + 39714816);     // 50176*1152  bf16 = 115,605,504 B
  bf16*  aout   = (bf16*)(ws + 155320320);    // 50176*384   bf16 = 38,535,168 B
  float* addend = (float*)(ws + 193855488);   // 64*12*49*64 f32  =  9,633,792 B

  // conversions (exact grids: sizes all divisible by 1024)
  cvt_f32_bf16<<<18816, 256, 0, stream>>>(x, xb);        // 19,267,584 elems
  cvt_f32_bf16<<<432, 256, 0, stream>>>(w_qkv, wqkvb);   //    442,368 elems
  cvt_f32_bf16<<<144, 256, 0, stream>>>(w_proj, wprojb); //    147,456 elems

  // fused bias+mask addend table
  build_addend<<<9408, 256, 0, stream>>>(mask, posidx, table, addend);

  // qkv = x @ w_qkv^T + b_qkv   (M=50176, N=1152, K=384)
  gemm_bt<true><<<392 * 9, 256, 0, stream>>>(xb, wqkvb, b_qkv, qkv, 50176, 1152, 384, 9, 392 * 9);

  // attention per (window-batch, head)
  attn_kernel<<<12288, 64, 0, stream>>>(qkv, addend, aout);

  // out = attn_out @ w_proj^T + b_proj   (M=50176, N=384, K=384)
  gemm_bt<false><<<392 * 3, 256, 0, stream>>>(aout, wprojb, b_proj, out, 50176, 384, 384, 3, 392 * 3);
}

// Round 4
// 187.242 us; speedup vs baseline: 1.0612x; 1.0612x over previous
//
#include <hip/hip_runtime.h>
#include <hip/hip_bf16.h>

typedef __hip_bfloat16 bf16;
typedef __attribute__((ext_vector_type(4))) float f32x4;
typedef __attribute__((ext_vector_type(8))) short bf16x8;  // 8 bf16 in 4 VGPRs
typedef __attribute__((ext_vector_type(4))) short bf16x4;  // 4 bf16 in 2 VGPRs

// ---------------------------------------------------------------------------
// helpers
// ---------------------------------------------------------------------------
__device__ __forceinline__ void gload_lds16(const bf16* g, bf16* l) {
  __builtin_amdgcn_global_load_lds(
      (const __attribute__((address_space(1))) unsigned int*)(const void*)g,
      (__attribute__((address_space(3))) unsigned int*)(void*)l,
      16, 0, 0);
}

// XCD-contiguous bijective swizzle; REQUIRES nwg % 8 == 0.
__device__ __forceinline__ int xcd_swz(int orig, int nwg) {
  return (orig & 7) * (nwg >> 3) + (orig >> 3);
}

// 16x16x16 bf16 MFMA (K=16): A-frag = lane{row=l&15, k=(l>>4)*4+0..3}
#if defined(__has_builtin)
#if __has_builtin(__builtin_amdgcn_mfma_f32_16x16x16bf16_1k)
#define HAVE_MFMA16_BUILTIN 1
#endif
#endif
__device__ __forceinline__ f32x4 mfma16(bf16x4 a, bf16x4 b, f32x4 c) {
#ifdef HAVE_MFMA16_BUILTIN
  return __builtin_amdgcn_mfma_f32_16x16x16bf16_1k(a, b, c, 0, 0, 0);
#else
  asm("v_mfma_f32_16x16x16_bf16 %0, %1, %2, %0" : "+v"(c) : "v"(a), "v"(b));
  return c;
#endif
}

// ---------------------------------------------------------------------------
// fp32 -> bf16 conversion (vectorized, exact grid)
// ---------------------------------------------------------------------------
__global__ void cvt_f32_bf16(const float* __restrict__ in, bf16* __restrict__ out) {
  size_t i = ((size_t)blockIdx.x * 256 + threadIdx.x) * 4;
  float4 v = *reinterpret_cast<const float4*>(in + i);
  bf16 o[4] = {__float2bfloat16(v.x), __float2bfloat16(v.y),
               __float2bfloat16(v.z), __float2bfloat16(v.w)};
  *reinterpret_cast<ushort4*>(out + i) = *reinterpret_cast<const ushort4*>(o);
}

// two small weight tensors in one launch
__global__ void cvt_two(const float* __restrict__ a, bf16* __restrict__ oa, int na4,
                        const float* __restrict__ b, bf16* __restrict__ ob) {
  int t = blockIdx.x * 256 + threadIdx.x;
  const float* src;
  bf16* dst;
  size_t i;
  if (t < na4) {
    src = a; dst = oa; i = (size_t)t * 4;
  } else {
    src = b; dst = ob; i = (size_t)(t - na4) * 4;
  }
  float4 v = *reinterpret_cast<const float4*>(src + i);
  bf16 o[4] = {__float2bfloat16(v.x), __float2bfloat16(v.y),
               __float2bfloat16(v.z), __float2bfloat16(v.w)};
  *reinterpret_cast<ushort4*>(dst + i) = *reinterpret_cast<const ushort4*>(o);
}

// ---------------------------------------------------------------------------
// addend[w][h][row][col64] = masked ? mask : table[pos_idx, h] ; col>=49 -> -1e30
// handles pos_idx stored as int32 OR int64 (odd-word-zero probe)
// ---------------------------------------------------------------------------
__global__ void build_addend(const float* __restrict__ mask, const int* __restrict__ pos,
                             const float* __restrict__ table, float* __restrict__ out) {
  int idx = blockIdx.x * 256 + threadIdx.x;   // total 64*12*49*64 = 2,408,448
  int col = idx & 63;
  int rh  = idx >> 6;
  int row = rh % 49;
  int h   = (rh / 49) % 12;
  int w   = rh / (49 * 12);
  float v = -1e30f;
  if (col < 49) {
    float m = mask[(w * 49 + row) * 49 + col];
    if (m != 0.0f) {
      v = m;
    } else {
      bool is64 = (pos[1] == 0) & (pos[3] == 0) & (pos[5] == 0) & (pos[7] == 0) &
                  (pos[9] == 0) & (pos[11] == 0) & (pos[13] == 0) & (pos[15] == 0);
      int pi = (w * 49 + row) * 49 + col;
      int p = is64 ? pos[2 * pi] : pos[pi];
      v = table[p * 12 + h];
    }
  }
  out[idx] = v;
}

// ---------------------------------------------------------------------------
// GEMM: C[M,N] = A[M,K] @ B[N,K]^T + bias[N]   (A,B bf16 row-major K-contig)
// 128x128 tile, BK=32, 4 waves (2x2 of 64x64), global_load_lds width 16.
// (BK=64 measured worse: 32KB LDS halves occupancy, 128B row stride trips
//  32-way bank conflicts — R3 counters.)
// ---------------------------------------------------------------------------
template <bool OUT_BF16>
__global__ __launch_bounds__(256) void gemm_bt(
    const bf16* __restrict__ A, const bf16* __restrict__ Bm,
    const float* __restrict__ bias, void* __restrict__ Cout,
    int M, int N, int K, int nbn, int nwg) {
  __shared__ bf16 As[128 * 32];
  __shared__ bf16 Bs[128 * 32];
  const int t = threadIdx.x;
  const int lane = t & 63;
  const int w = t >> 6, wr = w >> 1, wc = w & 1;
  const int lid = xcd_swz(blockIdx.x, nwg);
  const int bm = lid / nbn, bn = lid % nbn;
  const int lr = lane & 15, lg = lane >> 4;

  const bf16* ag = A + ((size_t)(bm * 128 + (t >> 2))) * K + (t & 3) * 8;
  const bf16* bg = Bm + ((size_t)(bn * 128 + (t >> 2))) * K + (t & 3) * 8;
  bf16* al = As + t * 8;
  bf16* bl = Bs + t * 8;
  const size_t rstep = (size_t)64 * K;

  f32x4 acc[4][4] = {};

  for (int k0 = 0; k0 < K; k0 += 32) {
    gload_lds16(ag + k0, al);
    gload_lds16(ag + k0 + rstep, al + 64 * 32);
    gload_lds16(bg + k0, bl);
    gload_lds16(bg + k0 + rstep, bl + 64 * 32);
    __syncthreads();
    bf16x8 af[4], bff[4];
    const bf16* ab = As + (wr * 64 + lr) * 32 + lg * 8;
    const bf16* bb = Bs + (wc * 64 + lr) * 32 + lg * 8;
#pragma unroll
    for (int i = 0; i < 4; i++) af[i] = *reinterpret_cast<const bf16x8*>(ab + i * 16 * 32);
#pragma unroll
    for (int j = 0; j < 4; j++) bff[j] = *reinterpret_cast<const bf16x8*>(bb + j * 16 * 32);
#pragma unroll
    for (int i = 0; i < 4; i++)
#pragma unroll
      for (int j = 0; j < 4; j++)
        acc[i][j] = __builtin_amdgcn_mfma_f32_16x16x32_bf16(af[i], bff[j], acc[i][j], 0, 0, 0);
    __syncthreads();
  }

#pragma unroll
  for (int i = 0; i < 4; i++) {
    int row0 = bm * 128 + wr * 64 + i * 16 + lg * 4;
#pragma unroll
    for (int j = 0; j < 4; j++) {
      int col = bn * 128 + wc * 64 + j * 16 + lr;
      float bv = bias[col];
#pragma unroll
      for (int r = 0; r < 4; r++) {
        float v = acc[i][j][r] + bv;
        if (OUT_BF16)
          ((bf16*)Cout)[(size_t)(row0 + r) * N + col] = __float2bfloat16(v);
        else
          ((float*)Cout)[(size_t)(row0 + r) * N + col] = v;
      }
    }
  }
}

// ---------------------------------------------------------------------------
// fused window attention: 1 wave per (b_, h). 49x49 scores padded to 64x64.
// qkv layout: [50176][1152] bf16, cols [0,384)=Q, [384,768)=K, [768,1152)=V.
// S^T = mfma(K,Q): lane holds P[q=qj*16+lr][k=ki*16+lg*4+r] -> that IS the
// A-fragment of mfma_f32_16x16x16_bf16, so PV runs from registers (no P LDS).
// ---------------------------------------------------------------------------
__global__ __launch_bounds__(64) void attn_kernel(
    const bf16* __restrict__ qkv, const float* __restrict__ addend,
    bf16* __restrict__ attn_out) {
  const int bid = xcd_swz(blockIdx.x, 12288);   // 12 consecutive bids share a window
  const int b = bid / 12;
  const int h = bid % 12;
  const int w = b & 63;
  const int lane = threadIdx.x;
  const int lr = lane & 15, lg = lane >> 4;
  const float scale = 0.17677669529663687f;  // 32^-0.5

  __shared__ ushort vT[32][72];     // V^T[d][k]

  const size_t base = (size_t)b * 49 * 1152;

  // --- Q, K fragments straight from global (rows >= 49 clamped to 48)
  bf16x8 qf[4], kf[4];
#pragma unroll
  for (int i = 0; i < 4; i++) {
    int rw = i * 16 + lr;
    int row = rw < 49 ? rw : 48;
    qf[i] = *reinterpret_cast<const bf16x8*>(qkv + base + (size_t)row * 1152 + h * 32 + lg * 8);
    kf[i] = *reinterpret_cast<const bf16x8*>(qkv + base + (size_t)row * 1152 + 384 + h * 32 + lg * 8);
  }

  // --- stage V transposed into LDS: vT[d][k] = V[k][d]; pad k>=49 with 0
  if (lane < 49) {
#pragma unroll
    for (int c4 = 0; c4 < 4; c4++) {
      bf16x8 vv = *reinterpret_cast<const bf16x8*>(
          qkv + base + (size_t)lane * 1152 + 768 + h * 32 + c4 * 8);
#pragma unroll
      for (int cc = 0; cc < 8; cc++) vT[c4 * 8 + cc][lane] = (ushort)vv[cc];
    }
  } else {
#pragma unroll
    for (int c = 0; c < 32; c++) vT[c][lane] = 0;
  }

  // --- per q-tile: S^T column, softmax over lane-local k, pack A-frags
  const float* add_base = addend + (size_t)(w * 12 + h) * 49 * 64;
  bf16x4 pa[4][4];   // [qj][ki]
#pragma unroll
  for (int qj = 0; qj < 4; qj++) {
    f32x4 s[4] = {};
    __builtin_amdgcn_s_setprio(1);
#pragma unroll
    for (int ki = 0; ki < 4; ki++)
      s[ki] = __builtin_amdgcn_mfma_f32_16x16x32_bf16(kf[ki], qf[qj], s[ki], 0, 0, 0);
    __builtin_amdgcn_s_setprio(0);

    int q = qj * 16 + lr;
    int qc = q < 49 ? q : 48;
    const float* ab_ = add_base + qc * 64;
    float v[16];
    float mx = -1e38f;
#pragma unroll
    for (int ki = 0; ki < 4; ki++) {
      float4 ad = *reinterpret_cast<const float4*>(ab_ + ki * 16 + lg * 4);
      v[ki * 4 + 0] = s[ki][0] * scale + ad.x;
      v[ki * 4 + 1] = s[ki][1] * scale + ad.y;
      v[ki * 4 + 2] = s[ki][2] * scale + ad.z;
      v[ki * 4 + 3] = s[ki][3] * scale + ad.w;
    }
#pragma unroll
    for (int u = 0; u < 16; u++) mx = fmaxf(mx, v[u]);
    mx = fmaxf(mx, __shfl_xor(mx, 16, 64));
    mx = fmaxf(mx, __shfl_xor(mx, 32, 64));
    float sum = 0.f;
#pragma unroll
    for (int u = 0; u < 16; u++) {
      v[u] = __expf(v[u] - mx);
      sum += v[u];
    }
    sum += __shfl_xor(sum, 16, 64);
    sum += __shfl_xor(sum, 32, 64);
    float rs = 1.0f / sum;
#pragma unroll
    for (int ki = 0; ki < 4; ki++) {
      bf16x4 p;
#pragma unroll
      for (int r = 0; r < 4; r++)
        p[r] = (short)__bfloat16_as_ushort(__float2bfloat16(v[ki * 4 + r] * rs));
      pa[qj][ki] = p;
    }
  }
  __syncthreads();   // vT ready

  // --- O = P @ V via 16x16x16: A=pa (in regs), B=V frag from vT
  f32x4 acc2[4][2] = {};
#pragma unroll
  for (int dt = 0; dt < 2; dt++) {
    bf16x4 vb[4];
#pragma unroll
    for (int ki = 0; ki < 4; ki++)
      vb[ki] = *reinterpret_cast<const bf16x4*>(&vT[dt * 16 + lr][ki * 16 + lg * 4]);
    __builtin_amdgcn_s_setprio(1);
#pragma unroll
    for (int qj = 0; qj < 4; qj++)
#pragma unroll
      for (int ki = 0; ki < 4; ki++)
        acc2[qj][dt] = mfma16(pa[qj][ki], vb[ki], acc2[qj][dt]);
    __builtin_amdgcn_s_setprio(0);
  }

  // --- store attn_out (bf16); P was pre-normalized
#pragma unroll
  for (int qj = 0; qj < 4; qj++)
#pragma unroll
    for (int r = 0; r < 4; r++) {
      int row = qj * 16 + lg * 4 + r;
      if (row < 49) {
#pragma unroll
        for (int dt = 0; dt < 2; dt++) {
          int col = h * 32 + dt * 16 + lr;
          attn_out[((size_t)b * 49 + row) * 384 + col] = __float2bfloat16(acc2[qj][dt][r]);
        }
      }
    }
}

// ---------------------------------------------------------------------------
// launch
// ---------------------------------------------------------------------------
extern "C" void kernel_launch(void* const* d_in, const int* in_sizes, int n_in,
                              void* d_out, int out_size, void* d_ws, size_t ws_size,
                              hipStream_t stream) {
  const float* x      = (const float*)d_in[0];
  const float* mask   = (const float*)d_in[1];
  const int*   posidx = (const int*)d_in[2];
  const float* table  = (const float*)d_in[3];
  const float* w_qkv  = (const float*)d_in[4];
  const float* b_qkv  = (const float*)d_in[5];
  const float* w_proj = (const float*)d_in[6];
  const float* b_proj = (const float*)d_in[7];
  float* out = (float*)d_out;

  char* ws = (char*)d_ws;
  bf16*  xb     = (bf16*)(ws + 0);            // 50176*384   bf16 = 38,535,168 B
  bf16*  wqkvb  = (bf16*)(ws + 38535168);     // 1152*384    bf16 =    884,736 B
  bf16*  wprojb = (bf16*)(ws + 39419904);     // 384*384     bf16 =    294,912 B
  bf16*  qkv    = (bf16*)(ws + 39714816);     // 50176*1152  bf16 = 115,605,504 B
  bf16*  aout   = (bf16*)(ws + 155320320);    // 50176*384   bf16 = 38,535,168 B
  float* addend = (float*)(ws + 193855488);   // 64*12*49*64 f32  =  9,633,792 B

  // conversions
  cvt_f32_bf16<<<18816, 256, 0, stream>>>(x, xb);                       // 19,267,584 elems
  cvt_two<<<576, 256, 0, stream>>>(w_qkv, wqkvb, 110592, w_proj, wprojb);

  // fused bias+mask addend table
  build_addend<<<9408, 256, 0, stream>>>(mask, posidx, table, addend);

  // qkv = x @ w_qkv^T + b_qkv   (M=50176, N=1152, K=384)
  gemm_bt<true><<<392 * 9, 256, 0, stream>>>(xb, wqkvb, b_qkv, qkv, 50176, 1152, 384, 9, 392 * 9);

  // attention per (window-batch, head)
  attn_kernel<<<12288, 64, 0, stream>>>(qkv, addend, aout);

  // out = attn_out @ w_proj^T + b_proj   (M=50176, N=384, K=384)
  gemm_bt<false><<<392 * 3, 256, 0, stream>>>(aout, wprojb, b_proj, out, 50176, 384, 384, 3, 392 * 3);
}